// Round 4
// baseline (183.289 us; speedup 1.0000x reference)
//
#include <hip/hip_runtime.h>
#include <hip/hip_bf16.h>

#define B_   8
#define SQ_  2048
#define SK_  2048
#define D_   128

typedef __attribute__((ext_vector_type(8))) _Float16 f16x8;
typedef __attribute__((ext_vector_type(4))) _Float16 f16x4;
typedef __attribute__((ext_vector_type(4))) float    f32x4;

// Fragment-major layouts (all f16), lane = l, hi = l>>4, ql = l&15:
//  Qf[b][qt:128][ks:4][l:64][8] : elem (b, q = qt*16+ql, d = ks*32+hi*8+j)
//  Kf[b][kt:128][ks:4][l:64][8] : elem (b, k = kt*16+ql, d = ks*32+hi*8+j)
//  Vf[b][kt:128][dt:8][l:64][4] : elem (b, k = kt*16+hi*4+j, d = dt*16+ql)
//  RZ[qt:128][kt:128][l:64][4]  : elem (q = qt*16+ql, k = kt*16+hi*4+j)
#define QK_BSTRIDE (128 * 4 * 64 * 8)   // 262144 elems per batch
#define V_BSTRIDE  (128 * 8 * 64 * 4)   // 262144 elems per batch

// ---------------------------------------------------------------------------
// Q,K fp32 -> fragment-major f16.  grid (1024, 2), block 256.
// ---------------------------------------------------------------------------
__global__ __launch_bounds__(256)
void qkprep(const float* __restrict__ Q, const float* __restrict__ K,
            _Float16* __restrict__ Qf, _Float16* __restrict__ Kf) {
    const float* src = blockIdx.y ? K : Q;
    _Float16*    dst = blockIdx.y ? Kf : Qf;
    int gid = blockIdx.x * 256 + threadIdx.x;          // 0..262143
    int l  = gid & 63;
    int ks = (gid >> 6) & 3;
    int t  = (gid >> 8) & 127;
    int b  = gid >> 15;
    const float* p = src + ((size_t)b * 2048 + t * 16 + (l & 15)) * 128
                         + ks * 32 + (l >> 4) * 8;
    f32x4 a = *(const f32x4*)p;
    f32x4 c = *(const f32x4*)(p + 4);
    f16x8 r;
    r[0] = (_Float16)a[0]; r[1] = (_Float16)a[1];
    r[2] = (_Float16)a[2]; r[3] = (_Float16)a[3];
    r[4] = (_Float16)c[0]; r[5] = (_Float16)c[1];
    r[6] = (_Float16)c[2]; r[7] = (_Float16)c[3];
    *(f16x8*)(dst + (size_t)gid * 8) = r;
}

// ---------------------------------------------------------------------------
// V fp32 -> fragment-major f16 (transposed frags). grid (32, 8), block 256.
// ---------------------------------------------------------------------------
__global__ __launch_bounds__(256)
void vprep(const float* __restrict__ V, _Float16* __restrict__ Vf) {
    __shared__ _Float16 T[64][136];
    const int b  = blockIdx.y;
    const int kb = blockIdx.x;           // 64 k-rows per block
    const int t  = threadIdx.x;
    const int row = t >> 2, c0 = (t & 3) * 32;
    const float* src = V + ((size_t)b * SK_ + kb * 64 + row) * D_ + c0;
#pragma unroll
    for (int u = 0; u < 8; ++u) {
        f32x4 v = *(const f32x4*)(src + u * 4);
        f16x4 h;
        h[0] = (_Float16)v[0]; h[1] = (_Float16)v[1];
        h[2] = (_Float16)v[2]; h[3] = (_Float16)v[3];
        *(f16x4*)&T[row][c0 + u * 4] = h;
    }
    __syncthreads();
#pragma unroll
    for (int u = 0; u < 8; ++u) {
        int slot = t + 256 * u;          // 0..2047
        int l  = slot & 63;
        int dt = (slot >> 6) & 7;
        int kt = slot >> 9;              // 0..3
        int hi = l >> 4, ql = l & 15;
        f16x4 r;
#pragma unroll
        for (int j = 0; j < 4; ++j) r[j] = T[kt * 16 + hi * 4 + j][dt * 16 + ql];
        *(f16x4*)(Vf + ((((size_t)b * 128 + kb * 4 + kt) * 8 + dt) * 64 + l) * 4) = r;
    }
}

// ---------------------------------------------------------------------------
// Phase 1: rz[q][k] = 1 / sum_b exp(S_b[q,k]/128), fragment-major output.
// block = 8 waves = 8 batches, 64x64 tile. grid 1024, block 512.
// ---------------------------------------------------------------------------
__global__ __launch_bounds__(512, 4)
void zred(const _Float16* __restrict__ Qf, const _Float16* __restrict__ Kf,
          _Float16* __restrict__ RZ) {
    __shared__ _Float16 E[8][64][64];   // 64 KB, 16B-granule XOR swizzle
    const int bid   = blockIdx.x;
    const int qtile = bid >> 5, ktile = bid & 31;
    const int b  = threadIdx.x >> 6;
    const int l  = threadIdx.x & 63;
    const int hi = l >> 4, ql = l & 15;

    const _Float16* Qb = Qf + (size_t)b * QK_BSTRIDE;
    const _Float16* Kb = Kf + (size_t)b * QK_BSTRIDE;

    // swapped S^T = mfma(K, Q): D lane holds k = kk*16+hi*4+r, q = qq*16+ql
    f32x4 s[4][4] = {};
#pragma unroll
    for (int ks = 0; ks < 4; ++ks) {
        f16x8 kf[4];
#pragma unroll
        for (int kk = 0; kk < 4; ++kk)
            kf[kk] = *(const f16x8*)(Kb + ((((size_t)ktile * 4 + kk) * 4 + ks) * 64 + l) * 8);
#pragma unroll
        for (int qq = 0; qq < 4; ++qq) {
            f16x8 qv = *(const f16x8*)(Qb + ((((size_t)qtile * 4 + qq) * 4 + ks) * 64 + l) * 8);
#pragma unroll
            for (int kk = 0; kk < 4; ++kk)
                s[kk][qq] = __builtin_amdgcn_mfma_f32_16x16x32_f16(kf[kk], qv, s[kk][qq], 0, 0, 0);
        }
    }

    f16x4* E4 = (f16x4*)&E[0][0][0];
#pragma unroll
    for (int kk = 0; kk < 4; ++kk)
#pragma unroll
        for (int qq = 0; qq < 4; ++qq) {
            f16x4 e;
#pragma unroll
            for (int r = 0; r < 4; ++r)
                e[r] = (_Float16)__expf(s[kk][qq][r] * 0.0078125f);
            int q = qq * 16 + ql;
            int k = kk * 16 + hi * 4;
            int g16 = ((b * 64 + q) << 3) + ((k >> 3) ^ (q & 7));
            E4[g16 * 2 + ((k >> 2) & 1)] = e;
        }
    __syncthreads();

    // per-thread strip: q = t>>3 (0..63), k0 = (t&7)*8
    const int t  = threadIdx.x;
    const int q  = t >> 3, k0 = (t & 7) * 8;
    const f16x8* E8 = (const f16x8*)&E[0][0][0];
    const int gsw = (k0 >> 3) ^ (q & 7);
    f16x8 z = E8[(0 * 64 + q) * 8 + gsw];
#pragma unroll
    for (int bb = 1; bb < 8; ++bb)
        z = z + E8[(bb * 64 + q) * 8 + gsw];

    float inv[8];
#pragma unroll
    for (int j = 0; j < 8; ++j) inv[j] = __builtin_amdgcn_rcpf((float)z[j]);

    const int gq = qtile * 64 + q;
    const int gk = ktile * 64 + k0;
#pragma unroll
    for (int h = 0; h < 2; ++h) {
        int k   = gk + 4 * h;
        int kt  = k >> 4;
        int lh  = ((k & 15) >> 2) * 16 + (gq & 15);
        f16x4 rzv;
#pragma unroll
        for (int j = 0; j < 4; ++j) rzv[j] = (_Float16)inv[4 * h + j];
        *(f16x4*)(RZ + ((((size_t)(gq >> 4)) * 128 + kt) * 64 + lh) * 4) = rzv;
    }
}

// ---------------------------------------------------------------------------
// Phase 2: out[b,qi*32..+31,:] = sum_k (exp(S/128) * rz) @ V.
// block = (b, 32-q-row tile), 8 waves = 8 k-slices of 256. LDS reduce,
// clean coalesced store — NO global atomics. b = bid&7 pins batch -> XCD.
// ---------------------------------------------------------------------------
__global__ __launch_bounds__(512, 3)
void av(const _Float16* __restrict__ Qf, const _Float16* __restrict__ Kf,
        const _Float16* __restrict__ Vf, const _Float16* __restrict__ RZ,
        float* __restrict__ out) {
    __shared__ float Obuf[32 * 128];

    const int bid = blockIdx.x;          // 512
    const int b   = bid & 7;             // batch -> XCD pinned
    const int qi  = bid >> 3;            // 0..63, 32 q-rows
    const int w   = threadIdx.x >> 6;    // wave = k-slice of 256
    const int l   = threadIdx.x & 63;
    const int hi  = l >> 4, ql = l & 15;

    for (int i = threadIdx.x; i < 32 * 128; i += 512) Obuf[i] = 0.0f;

    const _Float16* Qb = Qf + (size_t)b * QK_BSTRIDE;
    const _Float16* Kb = Kf + (size_t)b * QK_BSTRIDE;
    const _Float16* Vb = Vf + (size_t)b * V_BSTRIDE;

    f16x8 qf[2][4];
#pragma unroll
    for (int qq = 0; qq < 2; ++qq)
#pragma unroll
        for (int ks = 0; ks < 4; ++ks)
            qf[qq][ks] = *(const f16x8*)(Qb + ((((size_t)qi * 2 + qq) * 4 + ks) * 64 + l) * 8);

    f32x4 oacc[2][8] = {};
    __syncthreads();   // Obuf zero visible before epilogue atomics

    for (int it = 0; it < 8; ++it) {
        const int kt0 = w * 16 + it * 2;        // global 16-k tile base

        // S^T via swapped mfma: lane q = qq*16+ql, k = kk*16+hi*4+r
        f32x4 s[2][2] = {};
#pragma unroll
        for (int ks = 0; ks < 4; ++ks) {
            f16x8 k0 = *(const f16x8*)(Kb + ((((size_t)kt0 + 0) * 4 + ks) * 64 + l) * 8);
            f16x8 k1 = *(const f16x8*)(Kb + ((((size_t)kt0 + 1) * 4 + ks) * 64 + l) * 8);
#pragma unroll
            for (int qq = 0; qq < 2; ++qq) {
                s[0][qq] = __builtin_amdgcn_mfma_f32_16x16x32_f16(k0, qf[qq][ks], s[0][qq], 0, 0, 0);
                s[1][qq] = __builtin_amdgcn_mfma_f32_16x16x32_f16(k1, qf[qq][ks], s[1][qq], 0, 0, 0);
            }
        }

        // P fragment (16x16x16 A-layout) = exp(S/128) * rz — no repack needed
        f16x4 ph[2][2];
#pragma unroll
        for (int kk = 0; kk < 2; ++kk)
#pragma unroll
            for (int qq = 0; qq < 2; ++qq) {
                f16x4 rzv = *(const f16x4*)(RZ + ((((size_t)qi * 2 + qq) * 128 + kt0 + kk) * 64 + l) * 4);
                f16x4 p;
#pragma unroll
                for (int r = 0; r < 4; ++r)
                    p[r] = (_Float16)__expf(s[kk][qq][r] * 0.0078125f) * rzv[r];
                ph[qq][kk] = p;
            }

        // O += P @ V via 16x16x16 MFMA
#pragma unroll
        for (int dt = 0; dt < 8; ++dt) {
            f16x4 v0 = *(const f16x4*)(Vb + ((((size_t)kt0 + 0) * 8 + dt) * 64 + l) * 4);
            f16x4 v1 = *(const f16x4*)(Vb + ((((size_t)kt0 + 1) * 8 + dt) * 64 + l) * 4);
#pragma unroll
            for (int qq = 0; qq < 2; ++qq) {
                oacc[qq][dt] = __builtin_amdgcn_mfma_f32_16x16x16f16(ph[qq][0], v0, oacc[qq][dt], 0, 0, 0);
                oacc[qq][dt] = __builtin_amdgcn_mfma_f32_16x16x16f16(ph[qq][1], v1, oacc[qq][dt], 0, 0, 0);
            }
        }
    }

    // reduce the 8 k-slice partials in LDS (distinct addresses per lane)
#pragma unroll
    for (int qq = 0; qq < 2; ++qq)
#pragma unroll
        for (int dt = 0; dt < 8; ++dt)
#pragma unroll
            for (int r = 0; r < 4; ++r)
                atomicAdd(&Obuf[(qq * 16 + hi * 4 + r) * 128 + dt * 16 + ql],
                          oacc[qq][dt][r]);
    __syncthreads();

    // coalesced write-out: 512 threads x 8 f32
    const int idx = threadIdx.x * 8;
    const int q   = idx >> 7;
    const int d   = idx & 127;
    float* op = out + ((size_t)b * SQ_ + qi * 32 + q) * D_ + d;
    *(f32x4*)op       = *(f32x4*)&Obuf[idx];
    *(f32x4*)(op + 4) = *(f32x4*)&Obuf[idx + 4];
}

// ---------------------------------------------------------------------------
extern "C" void kernel_launch(void* const* d_in, const int* in_sizes, int n_in,
                              void* d_out, int out_size, void* d_ws, size_t ws_size,
                              hipStream_t stream) {
    const float* Q = (const float*)d_in[0];
    const float* K = (const float*)d_in[1];
    const float* V = (const float*)d_in[2];
    float* out = (float*)d_out;

    _Float16* Qf = (_Float16*)d_ws;                       // 4 MB
    _Float16* Kf = Qf + (size_t)B_ * QK_BSTRIDE;          // 4 MB
    _Float16* Vf = Kf + (size_t)B_ * QK_BSTRIDE;          // 4 MB
    _Float16* RZ = Vf + (size_t)B_ * V_BSTRIDE;           // 8 MB (21 MB total)

    qkprep<<<dim3(1024, 2), 256, 0, stream>>>(Q, K, Qf, Kf);
    vprep<<<dim3(32, B_), 256, 0, stream>>>(V, Vf);
    zred<<<1024, 512, 0, stream>>>(Qf, Kf, RZ);
    av<<<512, 512, 0, stream>>>(Qf, Kf, Vf, RZ, out);
}

// Round 5
// 69.167 us; speedup vs baseline: 2.6500x; 2.6500x over previous
//
#include <hip/hip_runtime.h>
#include <hip/hip_bf16.h>

#define B_   8
#define SQ_  2048
#define SK_  2048
#define D_   128

typedef __attribute__((ext_vector_type(8))) _Float16 f16x8;
typedef __attribute__((ext_vector_type(4))) _Float16 f16x4;
typedef __attribute__((ext_vector_type(4))) float    f32x4;

// Fragment-major layouts (f16), lane l, hi = l>>4, ql = l&15:
//  Qf[b][qt:128][ks:4][l][8] : elem (q = qt*16+ql, d = ks*32+hi*8+j)   (A-frag rows)
//  Kf[b][kt:128][ks:4][l][8] : elem (k = kt*16+ql, d = ks*32+hi*8+j)   (B-frag rows)
//  Vf[b][kt:64][dt:8][l][8]  : elem (k = kt*32+hi*8+j, d = dt*16+ql)   (B-frag for PV)
//  Pf[b][qtl][kt:64][l][8]   : elem (q = qtl*16+ql, k = kt*32+hi*8+j)  (A-frag for PV)
#define QK_BSTRIDE (128 * 4 * 64 * 8)   // 262144 elems per batch
#define VF_BSTRIDE (64 * 8 * 64 * 8)    // 262144 elems per batch

__device__ __forceinline__ void dma16(const void* g, void* l) {
    __builtin_amdgcn_global_load_lds(
        (const __attribute__((address_space(1))) unsigned int*)g,
        (__attribute__((address_space(3))) unsigned int*)l, 16, 0, 0);
}

// ---------------------------------------------------------------------------
// Q,K fp32 -> fragment-major f16.  grid (1024, 2), block 256.
// ---------------------------------------------------------------------------
__global__ __launch_bounds__(256)
void qkprep(const float* __restrict__ Q, const float* __restrict__ K,
            _Float16* __restrict__ Qf, _Float16* __restrict__ Kf) {
    const float* src = blockIdx.y ? K : Q;
    _Float16*    dst = blockIdx.y ? Kf : Qf;
    int gid = blockIdx.x * 256 + threadIdx.x;          // 0..262143
    int l  = gid & 63;
    int ks = (gid >> 6) & 3;
    int t  = (gid >> 8) & 127;
    int b  = gid >> 15;
    const float* p = src + ((size_t)b * 2048 + t * 16 + (l & 15)) * 128
                         + ks * 32 + (l >> 4) * 8;
    f32x4 a = *(const f32x4*)p;
    f32x4 c = *(const f32x4*)(p + 4);
    f16x8 r;
    r[0] = (_Float16)a[0]; r[1] = (_Float16)a[1];
    r[2] = (_Float16)a[2]; r[3] = (_Float16)a[3];
    r[4] = (_Float16)c[0]; r[5] = (_Float16)c[1];
    r[6] = (_Float16)c[2]; r[7] = (_Float16)c[3];
    *(f16x8*)(dst + (size_t)gid * 8) = r;
}

// ---------------------------------------------------------------------------
// V fp32 -> PV-B-fragment-major f16. grid (32, 8), block 256 (64 k-rows/blk).
// ---------------------------------------------------------------------------
__global__ __launch_bounds__(256)
void vprep(const float* __restrict__ V, _Float16* __restrict__ Vf) {
    __shared__ _Float16 T[64][136];
    const int b  = blockIdx.y;
    const int kb = blockIdx.x;
    const int t  = threadIdx.x;
    const int row = t >> 2, c0 = (t & 3) * 32;
    const float* src = V + ((size_t)b * SK_ + kb * 64 + row) * D_ + c0;
#pragma unroll
    for (int u = 0; u < 8; ++u) {
        f32x4 v = *(const f32x4*)(src + u * 4);
        f16x4 h;
        h[0] = (_Float16)v[0]; h[1] = (_Float16)v[1];
        h[2] = (_Float16)v[2]; h[3] = (_Float16)v[3];
        *(f16x4*)&T[row][c0 + u * 4] = h;
    }
    __syncthreads();
#pragma unroll
    for (int u = 0; u < 4; ++u) {
        int s   = u * 256 + t;            // 0..1023
        int l   = s & 63;
        int dt  = (s >> 6) & 7;
        int ktl = s >> 9;                 // 0..1
        int hi  = l >> 4, ql = l & 15;
        f16x8 r;
#pragma unroll
        for (int j = 0; j < 8; ++j) r[j] = T[ktl * 32 + hi * 8 + j][dt * 16 + ql];
        *(f16x8*)(Vf + (((size_t)b * 64 + kb * 2 + ktl) * 8 + dt) * 512 + (size_t)l * 8) = r;
    }
}

// ---------------------------------------------------------------------------
// Phase 1: P_b[q][k] = exp(S_b/128) / sum_b exp(S_b/128), written for ALL 8
// batches in PV-A-fragment-major layout. grid (nq/64)*32, block 512.
// ---------------------------------------------------------------------------
__global__ __launch_bounds__(512)
void zred(const _Float16* __restrict__ Qf, const _Float16* __restrict__ Kf,
          _Float16* __restrict__ Pf, int nqt, int qoff16) {
    __shared__ __attribute__((aligned(16))) _Float16 E[8][64][64];  // 64 KB
    const int bid   = blockIdx.x;
    const int qtile = bid >> 5;          // local to chunk
    const int ktile = bid & 31;
    const int b  = threadIdx.x >> 6;
    const int l  = threadIdx.x & 63;
    const int hi = l >> 4, ql = l & 15;

    const _Float16* Qb = Qf + (size_t)b * QK_BSTRIDE;
    const _Float16* Kb = Kf + (size_t)b * QK_BSTRIDE;

    // swapped S^T = mfma(K, Q): lane holds k = kk*16+hi*4+r, q = qq*16+ql
    f32x4 s[4][4] = {};
#pragma unroll
    for (int ks = 0; ks < 4; ++ks) {
        f16x8 kf[4];
#pragma unroll
        for (int kk = 0; kk < 4; ++kk)
            kf[kk] = *(const f16x8*)(Kb + ((((size_t)ktile * 4 + kk) * 4 + ks) * 64 + l) * 8);
#pragma unroll
        for (int qq = 0; qq < 4; ++qq) {
            f16x8 qv = *(const f16x8*)(Qb + ((((size_t)(qoff16 + qtile * 4 + qq)) * 4 + ks) * 64 + l) * 8);
#pragma unroll
            for (int kk = 0; kk < 4; ++kk)
                s[kk][qq] = __builtin_amdgcn_mfma_f32_16x16x32_f16(kf[kk], qv, s[kk][qq], 0, 0, 0);
        }
    }

    // E[b][q][k] = exp(S/128), 16B-granule XOR swizzle on k-group
    f16x4* E4 = (f16x4*)&E[0][0][0];
#pragma unroll
    for (int kk = 0; kk < 4; ++kk)
#pragma unroll
        for (int qq = 0; qq < 4; ++qq) {
            f16x4 e;
#pragma unroll
            for (int r = 0; r < 4; ++r)
                e[r] = (_Float16)__expf(s[kk][qq][r] * 0.0078125f);
            int q = qq * 16 + ql;
            int k = kk * 16 + hi * 4;
            int g16 = ((b * 64 + q) << 3) + ((k >> 3) ^ (q & 7));
            E4[g16 * 2 + ((k >> 2) & 1)] = e;
        }
    __syncthreads();

    // thread -> PV-A-frag slot: (ktl, qq2, lane)
    const int t    = threadIdx.x;
    const int ktl  = t >> 8;             // 0..1
    const int qq2  = (t >> 6) & 3;       // 0..3
    const int l2   = t & 63;
    const int hi2  = l2 >> 4, ql2 = l2 & 15;
    const int q_loc  = qq2 * 16 + ql2;
    const int k0_loc = ktl * 32 + hi2 * 8;
    const f16x8* E8  = (const f16x8*)&E[0][0][0];
    const int eidx   = (q_loc << 3) + ((k0_loc >> 3) ^ (q_loc & 7));

    // pass 1: z = sum_b e_b
    f16x8 z = E8[eidx];
#pragma unroll
    for (int bb = 1; bb < 8; ++bb) z = z + E8[bb * 512 + eidx];
    float inv[8];
#pragma unroll
    for (int j = 0; j < 8; ++j) inv[j] = __builtin_amdgcn_rcpf((float)z[j]);

    // pass 2: P_b = e_b * inv, coalesced f16x8 store per batch
    const size_t pbase = (((size_t)(qtile * 4 + qq2)) * 64 + (ktile * 2 + ktl)) * 512 + (size_t)l2 * 8;
#pragma unroll
    for (int bb = 0; bb < 8; ++bb) {
        f16x8 e = E8[bb * 512 + eidx];
        f16x8 p;
#pragma unroll
        for (int j = 0; j < 8; ++j) p[j] = (_Float16)((float)e[j] * inv[j]);
        *(f16x8*)(Pf + (size_t)bb * nqt * 32768 + pbase) = p;
    }
}

// ---------------------------------------------------------------------------
// Phase 2: O_b = P_b @ V_b — staged GEMM, global_load_lds double-buffer.
// grid (nq/64)*8, block 512. Block = (b, 64q); wave = 32q x 32d quadrant.
// K-step 64: stage P 8KB + V 16KB = 24 x 1KB DMA chunks (3 per wave).
// ---------------------------------------------------------------------------
__global__ __launch_bounds__(512)
void av(const _Float16* __restrict__ Pf, const _Float16* __restrict__ Vf,
        float* __restrict__ out, int nqt, int qoff) {
    __shared__ __attribute__((aligned(16))) _Float16 lds[2 * 12288];  // 2 x 24KB

    const int bid = blockIdx.x;
    const int b   = bid & 7;             // batch -> XCD pinned
    const int mt  = bid >> 3;            // 64-q M-tile (chunk-local)
    const int w   = threadIdx.x >> 6;
    const int l   = threadIdx.x & 63;
    const int wq  = w >> 2;              // 0..1
    const int wd  = w & 3;               // 0..3
    const int hi  = l >> 4, ql = l & 15;

    const _Float16* Pb = Pf + (size_t)b * nqt * 32768;
    const _Float16* Vb = Vf + (size_t)b * VF_BSTRIDE;

#define STAGE(bufi, kt2) do {                                                  \
    _Float16* dst0 = (_Float16*)lds + (bufi) * 12288;                          \
    _Pragma("unroll")                                                          \
    for (int u = 0; u < 3; ++u) {                                              \
        int c = w * 3 + u;                                                     \
        const _Float16* srcp;                                                  \
        if (c < 8)                                                             \
            srcp = Pb + (((size_t)(mt * 4 + (c >> 1))) * 64 + ((kt2) * 2 + (c & 1))) * 512 + (size_t)l * 8; \
        else {                                                                 \
            int cv = c - 8;                                                    \
            srcp = Vb + (((size_t)((kt2) * 2 + (cv >> 3))) * 8 + (cv & 7)) * 512 + (size_t)l * 8; \
        }                                                                      \
        dma16(srcp, dst0 + c * 512);                                           \
    }                                                                          \
} while (0)

    f32x4 acc[2][2] = {};
    int cur = 0;
    STAGE(0, 0);
    for (int kt2 = 0; kt2 < 32; ++kt2) {
        if (kt2 + 1 < 32) STAGE(cur ^ 1, kt2 + 1);
        __syncthreads();                         // drains vmcnt(0): buf[cur] ready
        const _Float16* Bf = (const _Float16*)lds + cur * 12288;
#pragma unroll
        for (int ktl = 0; ktl < 2; ++ktl) {
            f16x8 pfr[2], vfr[2];
#pragma unroll
            for (int i = 0; i < 2; ++i)
                pfr[i] = *(const f16x8*)(Bf + ((wq * 2 + i) * 2 + ktl) * 512 + l * 8);
#pragma unroll
            for (int j = 0; j < 2; ++j)
                vfr[j] = *(const f16x8*)(Bf + 4096 + (ktl * 8 + wd * 2 + j) * 512 + l * 8);
#pragma unroll
            for (int i = 0; i < 2; ++i)
#pragma unroll
                for (int j = 0; j < 2; ++j)
                    acc[i][j] = __builtin_amdgcn_mfma_f32_16x16x32_f16(pfr[i], vfr[j], acc[i][j], 0, 0, 0);
        }
        __syncthreads();                         // all reads done before overwrite
        cur ^= 1;
    }

    // D-layout: q = +hi*4+r, d = +ql ; each output element written once
    const int q0 = qoff + mt * 64 + wq * 32;
#pragma unroll
    for (int i = 0; i < 2; ++i)
#pragma unroll
        for (int j = 0; j < 2; ++j)
#pragma unroll
            for (int r = 0; r < 4; ++r)
                out[((size_t)b * SQ_ + q0 + i * 16 + hi * 4 + r) * D_ + (wd * 2 + j) * 16 + ql]
                    = acc[i][j][r];
#undef STAGE
}

// ---------------------------------------------------------------------------
extern "C" void kernel_launch(void* const* d_in, const int* in_sizes, int n_in,
                              void* d_out, int out_size, void* d_ws, size_t ws_size,
                              hipStream_t stream) {
    const float* Q = (const float*)d_in[0];
    const float* K = (const float*)d_in[1];
    const float* V = (const float*)d_in[2];
    float* out = (float*)d_out;

    _Float16* Qf = (_Float16*)d_ws;                       // 4 MB
    _Float16* Kf = Qf + (size_t)B_ * QK_BSTRIDE;          // 4 MB
    _Float16* Vf = Kf + (size_t)B_ * QK_BSTRIDE;          // 4 MB
    _Float16* Pf = Vf + (size_t)B_ * VF_BSTRIDE;          // up to 64 MB

    // fit P-chunk (nq q-rows): nq * 8b * 2048k * 2B = nq * 32KB
    size_t used  = (size_t)(12 * 1024 * 1024);
    size_t avail = ws_size > used ? (ws_size - used) / 2 : 0;   // f16 elems
    int nq = 2048;
    while (nq > 64 && (size_t)nq * 16384 > avail) nq >>= 1;
    int nchunks = 2048 / nq;
    int nqt = nq / 16;

    qkprep<<<dim3(1024, 2), 256, 0, stream>>>(Q, K, Qf, Kf);
    vprep<<<dim3(32, B_), 256, 0, stream>>>(V, Vf);

    for (int ci = 0; ci < nchunks; ++ci) {
        int qoff = ci * nq;
        zred<<<(nq / 64) * 32, 512, 0, stream>>>(Qf, Kf, Pf, nqt, qoff >> 4);
        av<<<(nq / 64) * 8, 512, 0, stream>>>(Pf, Vf, out, nqt, qoff);
    }
}

// Round 6
// 58.259 us; speedup vs baseline: 3.1461x; 1.1872x over previous
//
#include <hip/hip_runtime.h>
#include <hip/hip_bf16.h>

#define B_   8
#define SQ_  2048
#define SK_  2048
#define D_   128

typedef __attribute__((ext_vector_type(8))) _Float16 f16x8;
typedef __attribute__((ext_vector_type(4))) _Float16 f16x4;
typedef __attribute__((ext_vector_type(4))) float    f32x4;

// Fragment-major layouts (f16), lane l, hi = l>>4, ql = l&15:
//  Qf[b][qt:128][ks:4][l][8] : elem (q = qt*16+ql, d = ks*32+hi*8+j)   (A-frag rows)
//  Kf[b][kt:128][ks:4][l][8] : elem (k = kt*16+ql, d = ks*32+hi*8+j)   (B-frag rows)
//  Vf[b][kt:64][dt:8][l][8]  : elem (k = kt*32+hi*8+j, d = dt*16+ql)   (B-frag for PV)
//  Pf[b][qtl][kt:64][l][8]   : elem (q = qtl*16+ql, k = kt*32+hi*8+j)  (A-frag for PV)
#define QK_BSTRIDE (128 * 4 * 64 * 8)   // 262144 elems per batch
#define VF_BSTRIDE (64 * 8 * 64 * 8)    // 262144 elems per batch

__device__ __forceinline__ void dma16(const void* g, void* l) {
    __builtin_amdgcn_global_load_lds(
        (const __attribute__((address_space(1))) unsigned int*)g,
        (__attribute__((address_space(3))) unsigned int*)l, 16, 0, 0);
}

// ---------------------------------------------------------------------------
// prep: blocks 0..2047 -> Q,K fp32 -> fragment-major f16
//       blocks 2048..2303 -> V fp32 -> PV-B-fragment-major f16
// ---------------------------------------------------------------------------
__global__ __launch_bounds__(256)
void prep(const float* __restrict__ Q, const float* __restrict__ K,
          const float* __restrict__ V,
          _Float16* __restrict__ Qf, _Float16* __restrict__ Kf,
          _Float16* __restrict__ Vf) {
    __shared__ _Float16 T[64][136];
    const int bid = blockIdx.x;
    if (bid < 2048) {
        const float* src = (bid >= 1024) ? K : Q;
        _Float16*    dst = (bid >= 1024) ? Kf : Qf;
        int gid = (bid & 1023) * 256 + threadIdx.x;     // 0..262143
        int l  = gid & 63;
        int ks = (gid >> 6) & 3;
        int t  = (gid >> 8) & 127;
        int b  = gid >> 15;
        const float* p = src + ((size_t)b * 2048 + t * 16 + (l & 15)) * 128
                             + ks * 32 + (l >> 4) * 8;
        f32x4 a = *(const f32x4*)p;
        f32x4 c = *(const f32x4*)(p + 4);
        f16x8 r;
        r[0] = (_Float16)a[0]; r[1] = (_Float16)a[1];
        r[2] = (_Float16)a[2]; r[3] = (_Float16)a[3];
        r[4] = (_Float16)c[0]; r[5] = (_Float16)c[1];
        r[6] = (_Float16)c[2]; r[7] = (_Float16)c[3];
        *(f16x8*)(dst + (size_t)gid * 8) = r;
    } else {
        const int vb = bid - 2048;           // 0..255
        const int b  = vb >> 5;
        const int kb = vb & 31;
        const int t  = threadIdx.x;
        const int row = t >> 2, c0 = (t & 3) * 32;
        const float* src = V + ((size_t)b * SK_ + kb * 64 + row) * D_ + c0;
#pragma unroll
        for (int u = 0; u < 8; ++u) {
            f32x4 v = *(const f32x4*)(src + u * 4);
            f16x4 h;
            h[0] = (_Float16)v[0]; h[1] = (_Float16)v[1];
            h[2] = (_Float16)v[2]; h[3] = (_Float16)v[3];
            *(f16x4*)&T[row][c0 + u * 4] = h;
        }
        __syncthreads();
#pragma unroll
        for (int u = 0; u < 4; ++u) {
            int s   = u * 256 + t;            // 0..1023
            int l   = s & 63;
            int dt  = (s >> 6) & 7;
            int ktl = s >> 9;                 // 0..1
            int hi  = l >> 4, ql = l & 15;
            f16x8 r;
#pragma unroll
            for (int j = 0; j < 8; ++j) r[j] = T[ktl * 32 + hi * 8 + j][dt * 16 + ql];
            *(f16x8*)(Vf + (((size_t)b * 64 + kb * 2 + ktl) * 8 + dt) * 512 + (size_t)l * 8) = r;
        }
    }
}

// ---------------------------------------------------------------------------
// Phase 1: P_b[q][k] = exp(S_b/128) / sum_b exp(S_b/128), written for ALL 8
// batches in PV-A-fragment-major layout. grid (nq/64)*32, block 512.
// bid decode (qtile = bid>>5, ktile = bid&31) keeps each XCD's K working set
// at 4 k-tiles (0.5 MB, L2-resident) and Q tiles temporally L2-hot.
// ---------------------------------------------------------------------------
__global__ __launch_bounds__(512, 4)
void zred(const _Float16* __restrict__ Qf, const _Float16* __restrict__ Kf,
          _Float16* __restrict__ Pf, int nqt, int qoff16) {
    __shared__ __attribute__((aligned(16))) _Float16 E[8][64][64];  // 64 KB
    const int bid   = blockIdx.x;
    const int qtile = bid >> 5;          // local to chunk
    const int ktile = bid & 31;
    const int b  = threadIdx.x >> 6;
    const int l  = threadIdx.x & 63;
    const int hi = l >> 4, ql = l & 15;

    const _Float16* Qb = Qf + (size_t)b * QK_BSTRIDE;
    const _Float16* Kb = Kf + (size_t)b * QK_BSTRIDE;

    // swapped S^T = mfma(K, Q): lane holds k = kk*16+hi*4+r, q = qq*16+ql
    f32x4 s[4][4] = {};
#pragma unroll
    for (int ks = 0; ks < 4; ++ks) {
        f16x8 kf[4];
#pragma unroll
        for (int kk = 0; kk < 4; ++kk)
            kf[kk] = *(const f16x8*)(Kb + ((((size_t)ktile * 4 + kk) * 4 + ks) * 64 + l) * 8);
#pragma unroll
        for (int qq = 0; qq < 4; ++qq) {
            f16x8 qv = *(const f16x8*)(Qb + ((((size_t)(qoff16 + qtile * 4 + qq)) * 4 + ks) * 64 + l) * 8);
#pragma unroll
            for (int kk = 0; kk < 4; ++kk)
                s[kk][qq] = __builtin_amdgcn_mfma_f32_16x16x32_f16(kf[kk], qv, s[kk][qq], 0, 0, 0);
        }
    }

    // E[b][q][k] = exp(S/128), 16B-granule XOR swizzle on k-group
    f16x4* E4 = (f16x4*)&E[0][0][0];
#pragma unroll
    for (int kk = 0; kk < 4; ++kk)
#pragma unroll
        for (int qq = 0; qq < 4; ++qq) {
            f16x4 e;
#pragma unroll
            for (int r = 0; r < 4; ++r)
                e[r] = (_Float16)__expf(s[kk][qq][r] * 0.0078125f);
            int q = qq * 16 + ql;
            int k = kk * 16 + hi * 4;
            int g16 = ((b * 64 + q) << 3) + ((k >> 3) ^ (q & 7));
            E4[g16 * 2 + ((k >> 2) & 1)] = e;
        }
    __syncthreads();

    // thread -> PV-A-frag slot: (ktl, qq2, lane)
    const int t    = threadIdx.x;
    const int ktl  = t >> 8;             // 0..1
    const int qq2  = (t >> 6) & 3;       // 0..3
    const int l2   = t & 63;
    const int hi2  = l2 >> 4, ql2 = l2 & 15;
    const int q_loc  = qq2 * 16 + ql2;
    const int k0_loc = ktl * 32 + hi2 * 8;
    const f16x8* E8  = (const f16x8*)&E[0][0][0];
    const int eidx   = (q_loc << 3) + ((k0_loc >> 3) ^ (q_loc & 7));

    // pass 1: z = sum_b e_b
    f16x8 z = E8[eidx];
#pragma unroll
    for (int bb = 1; bb < 8; ++bb) z = z + E8[bb * 512 + eidx];
    float inv[8];
#pragma unroll
    for (int j = 0; j < 8; ++j) inv[j] = __builtin_amdgcn_rcpf((float)z[j]);

    // pass 2: P_b = e_b * inv, coalesced f16x8 store per batch
    const size_t pbase = (((size_t)(qtile * 4 + qq2)) * 64 + (ktile * 2 + ktl)) * 512 + (size_t)l2 * 8;
#pragma unroll
    for (int bb = 0; bb < 8; ++bb) {
        f16x8 e = E8[bb * 512 + eidx];
        f16x8 p;
#pragma unroll
        for (int j = 0; j < 8; ++j) p[j] = (_Float16)((float)e[j] * inv[j]);
        *(f16x8*)(Pf + (size_t)bb * nqt * 32768 + pbase) = p;
    }
}

// ---------------------------------------------------------------------------
// Phase 2: O_b = P_b @ V_b — staged GEMM, global_load_lds TRIPLE-buffer with
// counted vmcnt (depth-2 prefetch; loads stay in flight across barriers).
// grid (nq/64)*8, block 512. Block = (b, 64q); wave = 32q x 32d quadrant.
// K-step 64: stage P 8KB + V 16KB = 24 x 1KB DMA chunks (3 per wave).
// ---------------------------------------------------------------------------
__global__ __launch_bounds__(512)
void av(const _Float16* __restrict__ Pf, const _Float16* __restrict__ Vf,
        float* __restrict__ out, int nqt, int qoff) {
    __shared__ __attribute__((aligned(16))) _Float16 lds[3 * 12288];  // 3 x 24KB

    const int bid = blockIdx.x;
    const int b   = bid & 7;             // batch -> XCD pinned (V_b L2-resident)
    const int mt  = bid >> 3;            // 64-q M-tile (chunk-local)
    const int w   = threadIdx.x >> 6;
    const int l   = threadIdx.x & 63;
    const int wq  = w >> 2;              // 0..1
    const int wd  = w & 3;               // 0..3
    const int hi  = l >> 4, ql = l & 15;

    const _Float16* Pb = Pf + (size_t)b * nqt * 32768;
    const _Float16* Vb = Vf + (size_t)b * VF_BSTRIDE;

#define STAGE(bufi, kt2) do {                                                  \
    _Float16* dst0 = (_Float16*)lds + (size_t)(bufi) * 12288;                  \
    _Pragma("unroll")                                                          \
    for (int u = 0; u < 3; ++u) {                                              \
        int c = w * 3 + u;                                                     \
        const _Float16* srcp;                                                  \
        if (c < 8)                                                             \
            srcp = Pb + (((size_t)(mt * 4 + (c >> 1))) * 64 + ((kt2) * 2 + (c & 1))) * 512 + (size_t)l * 8; \
        else {                                                                 \
            int cv = c - 8;                                                    \
            srcp = Vb + (((size_t)((kt2) * 2 + (cv >> 3))) * 8 + (cv & 7)) * 512 + (size_t)l * 8; \
        }                                                                      \
        dma16(srcp, dst0 + c * 512);                                           \
    }                                                                          \
} while (0)

#define MFMA_PHASE(bufi) do {                                                  \
    const _Float16* Bf = (const _Float16*)lds + (size_t)(bufi) * 12288;        \
    _Pragma("unroll")                                                          \
    for (int ktl = 0; ktl < 2; ++ktl) {                                        \
        f16x8 pfr[2], vfr[2];                                                  \
        _Pragma("unroll")                                                      \
        for (int i = 0; i < 2; ++i)                                            \
            pfr[i] = *(const f16x8*)(Bf + ((wq * 2 + i) * 2 + ktl) * 512 + l * 8); \
        _Pragma("unroll")                                                      \
        for (int j = 0; j < 2; ++j)                                            \
            vfr[j] = *(const f16x8*)(Bf + 4096 + (ktl * 8 + wd * 2 + j) * 512 + l * 8); \
        _Pragma("unroll")                                                      \
        for (int i = 0; i < 2; ++i)                                            \
            _Pragma("unroll")                                                  \
            for (int j = 0; j < 2; ++j)                                        \
                acc[i][j] = __builtin_amdgcn_mfma_f32_16x16x32_f16(pfr[i], vfr[j], acc[i][j], 0, 0, 0); \
    }                                                                          \
} while (0)

    f32x4 acc[2][2] = {};
    STAGE(0, 0);
    STAGE(1, 1);
    for (int kt2 = 0; kt2 < 32; ++kt2) {
        if (kt2 < 30) {
            STAGE((kt2 + 2) % 3, kt2 + 2);
            // current tile's 3 DMAs done; 6 (2 tiles) may remain in flight
            asm volatile("s_waitcnt vmcnt(6)" ::: "memory");
        } else if (kt2 == 30) {
            asm volatile("s_waitcnt vmcnt(3)" ::: "memory");
        } else {
            asm volatile("s_waitcnt vmcnt(0)" ::: "memory");
        }
        __builtin_amdgcn_s_barrier();          // all waves' DMAs for this buf done
        __builtin_amdgcn_sched_barrier(0);     // no ds_read hoisting above
        MFMA_PHASE(kt2 % 3);
        __builtin_amdgcn_s_barrier();          // reads done before buf reuse
    }

    // D-layout: q = +hi*4+r, d = +ql ; each output element written once
    const int q0 = qoff + mt * 64 + wq * 32;
#pragma unroll
    for (int i = 0; i < 2; ++i)
#pragma unroll
        for (int j = 0; j < 2; ++j)
#pragma unroll
            for (int r = 0; r < 4; ++r)
                out[((size_t)b * SQ_ + q0 + i * 16 + hi * 4 + r) * D_ + (wd * 2 + j) * 16 + ql]
                    = acc[i][j][r];
#undef STAGE
#undef MFMA_PHASE
}

// ---------------------------------------------------------------------------
extern "C" void kernel_launch(void* const* d_in, const int* in_sizes, int n_in,
                              void* d_out, int out_size, void* d_ws, size_t ws_size,
                              hipStream_t stream) {
    const float* Q = (const float*)d_in[0];
    const float* K = (const float*)d_in[1];
    const float* V = (const float*)d_in[2];
    float* out = (float*)d_out;

    _Float16* Qf = (_Float16*)d_ws;                       // 4 MB
    _Float16* Kf = Qf + (size_t)B_ * QK_BSTRIDE;          // 4 MB
    _Float16* Vf = Kf + (size_t)B_ * QK_BSTRIDE;          // 4 MB
    _Float16* Pf = Vf + (size_t)B_ * VF_BSTRIDE;          // up to 64 MB

    // fit P-chunk (nq q-rows): nq * 8b * 2048k * 2B = nq * 32KB
    size_t used  = (size_t)(12 * 1024 * 1024);
    size_t avail = ws_size > used ? (ws_size - used) / 2 : 0;   // f16 elems
    int nq = 2048;
    while (nq > 64 && (size_t)nq * 16384 > avail) nq >>= 1;
    int nchunks = 2048 / nq;
    int nqt = nq / 16;

    prep<<<2048 + 256, 256, 0, stream>>>(Q, K, V, Qf, Kf, Vf);

    for (int ci = 0; ci < nchunks; ++ci) {
        int qoff = ci * nq;
        zred<<<(nq / 64) * 32, 512, 0, stream>>>(Qf, Kf, Pf, nqt, qoff >> 4);
        av<<<(nq / 64) * 8, 512, 0, stream>>>(Pf, Vf, out, nqt, qoff);
    }
}